// Round 10
// baseline (518.085 us; speedup 1.0000x reference)
//
#include <hip/hip_runtime.h>
#include <cstdint>
#include <cstddef>

// ---------------------------------------------------------------------------
// Performer block. fp32 in/out, bf16 MFMA internally.
// R10 = R7 (proven 503us pipeline) + mega2 fusing ONLY {LN2, mlp1+gelu,
// mlp2+y residual} -> out. The ya/proj half stays as R7's proven gemm_tn
// launches (bisecting the R9 mega bug: its remaining suspects - ya GEMM0,
// v-landing transpose, proj RMW - are excluded here).
// ws peak ~224 MB.
// ---------------------------------------------------------------------------

typedef __attribute__((ext_vector_type(8))) short s16x8;
typedef __attribute__((ext_vector_type(4))) short s16x4;
typedef __attribute__((ext_vector_type(4))) float fx4;
typedef __attribute__((ext_vector_type(8))) float fx8;

__device__ __forceinline__ float bf2f(short s) {
  union { float f; unsigned u; } z; z.u = ((unsigned)(unsigned short)s) << 16; return z.f;
}
__device__ __forceinline__ short f2bf(float f) {
  union { float f; unsigned u; } z; z.f = f;
  unsigned u = z.u;
  u += 0x7fffu + ((u >> 16) & 1u);   // RNE
  return (short)(u >> 16);
}

__device__ __forceinline__ void mfma_bf16(fx4& d, s16x8 a, s16x8 b) {
  asm("v_mfma_f32_16x16x32_bf16 %0, %1, %2, %0" : "+v"(d) : "v"(a), "v"(b));
}

enum : int { M_BIAS=1, M_EXP=2, M_DIV=4, M_RESID=8, M_GELU=16, M_TSTORE=32,
             M_BATCHBT=64, M_KQVT=128, M_RESIDT=256, M_F32OUT=512 };

// C[row][col] = sum_k A[row][k] * Bt[col][k]  (both operands k-contiguous bf16)
// Col-fast grid + bijective XCD chunk swizzle (nwg % 8 == 0).
// LDS: single 32KB buffer, 2-barrier loop, reg-staged prefetch.
// Chunk XOR-swizzle (store+read) keeps ds_read_b128 conflict-free.
template<int BM, int BN, int MODE>
__global__ __launch_bounds__(256)
void gemm_tn(const short* __restrict__ A, int lda,
             const short* __restrict__ Bt, int ldbt, long btStride,
             short* __restrict__ C, int ldc,
             int K,
             const float* __restrict__ bias,
             const float* __restrict__ rowvec, float escale,
             const short* __restrict__ resid, int ldr, int rcol,
             short* __restrict__ vt)
{
  constexpr int WM = BM / 2, WN = BN / 2, MR = WM / 16, NR = WN / 16;
  constexpr int AIT = BM * 8 / 256, BIT = BN * 8 / 256;
  __shared__ __align__(16) short Al[BM][64];
  __shared__ __align__(16) short Bl[BN][64];

  const int tid = threadIdx.x;
  const int gx = gridDim.x;
  const int nwg = gx * gridDim.y;
  const int o = blockIdx.x + gx * blockIdx.y;        // hw dispatch order id
  const int swz = (o & 7) * (nwg >> 3) + (o >> 3);   // bijective for nwg%8==0
  const int bx = swz % gx, by = swz / gx;            // col fast within chunk
  const int row0 = by * BM, col0 = bx * BN;

  const short* Bt2 = (MODE & M_BATCHBT)
      ? Bt + (size_t)(row0 >> 13) * (size_t)btStride : Bt;
  const int w = tid >> 6, l = tid & 63;
  const int wr = w >> 1, wc = w & 1;
  const int lr = l & 15, lk = l >> 4;

  fx4 acc[MR][NR];
#pragma unroll
  for (int m = 0; m < MR; ++m)
#pragma unroll
    for (int n = 0; n < NR; ++n)
#pragma unroll
      for (int j = 0; j < 4; ++j) acc[m][n][j] = 0.0f;

  s16x8 areg[AIT], breg[BIT];

  auto loadA = [&](int kt) {
    const short* p = A + (size_t)row0 * lda + kt * 64;
#pragma unroll
    for (int i = 0; i < AIT; ++i) {
      int ch = i * 256 + tid;
      areg[i] = *(const s16x8*)(p + (size_t)(ch >> 3) * lda + ((ch & 7) * 8));
    }
  };
  auto loadB = [&](int kt) {
    const short* p = Bt2 + (size_t)col0 * ldbt + kt * 64;
#pragma unroll
    for (int i = 0; i < BIT; ++i) {
      int ch = i * 256 + tid;
      breg[i] = *(const s16x8*)(p + (size_t)(ch >> 3) * ldbt + ((ch & 7) * 8));
    }
  };
  // swizzled LDS store: chunk (ch&7) ^ (row&7)
  auto storeA = [&]() {
#pragma unroll
    for (int i = 0; i < AIT; ++i) {
      int ch = i * 256 + tid, row = ch >> 3;
      *(s16x8*)&Al[row][((ch ^ row) & 7) * 8] = areg[i];
    }
  };
  auto storeB = [&]() {
#pragma unroll
    for (int i = 0; i < BIT; ++i) {
      int ch = i * 256 + tid, row = ch >> 3;
      *(s16x8*)&Bl[row][((ch ^ row) & 7) * 8] = breg[i];
    }
  };

  const int NT = K / 64;
  loadA(0); loadB(0); storeA(); storeB();
  __syncthreads();
  for (int kt = 0; kt < NT; ++kt) {
    if (kt + 1 < NT) { loadA(kt + 1); loadB(kt + 1); }
#pragma unroll
    for (int kk = 0; kk < 2; ++kk) {
      s16x8 af[MR], bfr[NR];
#pragma unroll
      for (int m = 0; m < MR; ++m) {
        const int ar = wr * WM + m * 16 + lr;
        af[m] = *(const s16x8*)&Al[ar][(((kk * 4 + lk) ^ ar) & 7) * 8];
      }
#pragma unroll
      for (int n = 0; n < NR; ++n) {
        const int br = wc * WN + n * 16 + lr;
        bfr[n] = *(const s16x8*)&Bl[br][(((kk * 4 + lk) ^ br) & 7) * 8];
      }
#pragma unroll
      for (int m = 0; m < MR; ++m)
#pragma unroll
        for (int n = 0; n < NR; ++n)
          mfma_bf16(acc[m][n], af[m], bfr[n]);
    }
    if (kt + 1 < NT) {
      __syncthreads();            // all reads of the buffer done
      storeA(); storeB();         // overwrite with next tile
      __syncthreads();            // stores visible
    }
  }

  // C/D layout (m89): col = lane&15, row = (lane>>4)*4 + j.
#pragma unroll
  for (int m = 0; m < MR; ++m) {
#pragma unroll
    for (int n = 0; n < NR; ++n) {
      const int gcol = col0 + wc * WN + n * 16 + lr;
      const float bv = (MODE & M_BIAS) ? bias[gcol] : 0.0f;
#pragma unroll
      for (int j = 0; j < 4; ++j) {
        const int grow = row0 + wr * WM + m * 16 + lk * 4 + j;
        float v = acc[m][n][j] + bv;
        if (MODE & M_EXP)  v = expf(v - rowvec[grow]) * escale;
        if (MODE & M_DIV)  v = v / (rowvec[grow] + 1e-8f);
        if (MODE & M_GELU) v = 0.5f * v * (1.0f + erff(v * 0.70710678118654752f));
        if (MODE & M_RESID)  v += bf2f(resid[(size_t)grow * ldr + rcol + gcol]);
        if (MODE & M_RESIDT) v += bf2f(resid[((size_t)((grow >> 13) * ldr + gcol)) * 8192 + (grow & 8191)]);
        if (MODE & M_F32OUT) {
          ((float*)C)[(size_t)grow * ldc + gcol] = v;
        } else if (MODE & M_TSTORE) {
          C[((size_t)((grow >> 13) * ldc + gcol)) * 8192 + (grow & 8191)] = f2bf(v);
        } else if (MODE & M_KQVT) {
          if (gcol < 768) C[(size_t)grow * 768 + gcol] = f2bf(v);
          else vt[((size_t)((grow >> 13) * 384 + (gcol - 768))) * 8192 + (grow & 8191)] = f2bf(v);
        } else {
          C[(size_t)grow * ldc + gcol] = f2bf(v);
        }
      }
    }
  }
}

// kptv partials: part[z=b*8+s][n][m] = sum_{t in split s} v[t,n]*kp[t,m]
__global__ __launch_bounds__(256)
void gemm_kptv(const short* __restrict__ vT, const short* __restrict__ kpT,
               float* __restrict__ part)
{
  __shared__ __align__(16) short Al[128][64];
  __shared__ __align__(16) short Bl[64][64];
  const int tid = threadIdx.x;
  const int b = blockIdx.z >> 3, s = blockIdx.z & 7;
  const int row0 = blockIdx.x * 128, col0 = blockIdx.y * 64;
  const short* A  = vT  + ((size_t)(b * 384 + row0)) * 8192 + s * 1024;
  const short* Bt = kpT + ((size_t)(b * 192 + col0)) * 8192 + s * 1024;
  const int w = tid >> 6, l = tid & 63;
  const int wr = w >> 1, wc = w & 1, lr = l & 15, lk = l >> 4;

  fx4 acc[4][2];
#pragma unroll
  for (int m = 0; m < 4; ++m)
#pragma unroll
    for (int n = 0; n < 2; ++n)
#pragma unroll
      for (int j = 0; j < 4; ++j) acc[m][n][j] = 0.0f;

  s16x8 areg[4], breg[2];
  auto loadA = [&](int kt) {
#pragma unroll
    for (int i = 0; i < 4; ++i) {
      int ch = i * 256 + tid;
      areg[i] = *(const s16x8*)(A + kt * 64 + (size_t)(ch >> 3) * 8192 + ((ch & 7) * 8));
    }
  };
  auto loadB = [&](int kt) {
#pragma unroll
    for (int i = 0; i < 2; ++i) {
      int ch = i * 256 + tid;
      breg[i] = *(const s16x8*)(Bt + kt * 64 + (size_t)(ch >> 3) * 8192 + ((ch & 7) * 8));
    }
  };
  auto storeA = [&]() {
#pragma unroll
    for (int i = 0; i < 4; ++i) {
      int ch = i * 256 + tid, row = ch >> 3;
      *(s16x8*)&Al[row][((ch ^ row) & 7) * 8] = areg[i];
    }
  };
  auto storeB = [&]() {
#pragma unroll
    for (int i = 0; i < 2; ++i) {
      int ch = i * 256 + tid, row = ch >> 3;
      *(s16x8*)&Bl[row][((ch ^ row) & 7) * 8] = breg[i];
    }
  };

  loadA(0); loadB(0); storeA(); storeB();
  __syncthreads();
  for (int kt = 0; kt < 16; ++kt) {
    if (kt + 1 < 16) { loadA(kt + 1); loadB(kt + 1); }
#pragma unroll
    for (int kk = 0; kk < 2; ++kk) {
      s16x8 af[4], bfr[2];
#pragma unroll
      for (int m = 0; m < 4; ++m) {
        const int ar = wr * 64 + m * 16 + lr;
        af[m] = *(const s16x8*)&Al[ar][(((kk * 4 + lk) ^ ar) & 7) * 8];
      }
#pragma unroll
      for (int n = 0; n < 2; ++n) {
        const int br = wc * 32 + n * 16 + lr;
        bfr[n] = *(const s16x8*)&Bl[br][(((kk * 4 + lk) ^ br) & 7) * 8];
      }
#pragma unroll
      for (int m = 0; m < 4; ++m)
#pragma unroll
        for (int n = 0; n < 2; ++n)
          mfma_bf16(acc[m][n], af[m], bfr[n]);
    }
    if (kt + 1 < 16) {
      __syncthreads();
      storeA(); storeB();
      __syncthreads();
    }
  }

  float* outp = part + (size_t)blockIdx.z * 73728;
#pragma unroll
  for (int m = 0; m < 4; ++m)
#pragma unroll
    for (int n = 0; n < 2; ++n) {
      const int gm = col0 + wc * 32 + n * 16 + lr;
#pragma unroll
      for (int j = 0; j < 4; ++j) {
        const int gn = row0 + wr * 64 + m * 16 + lk * 4 + j;
        outp[(size_t)gn * 192 + gm] = acc[m][n][j];
      }
    }
}

__global__ void kptv_reduce(const float* __restrict__ part, short* __restrict__ outb)
{
  const int i = blockIdx.x * 256 + threadIdx.x;   // i = b*73728 + n*192 + m
  const int b = i / 73728, j = i - b * 73728;
  const float* p = part + (size_t)b * 8 * 73728 + j;
  float s = 0.0f;
#pragma unroll
  for (int k = 0; k < 8; ++k) s += p[(size_t)k * 73728];
  outb[i] = f2bf(s);
}

// LayerNorm over 384, one wave per token.
template<typename T>
__global__ __launch_bounds__(256)
void ln_kernel(const T* __restrict__ in, const float* __restrict__ g,
               const float* __restrict__ bta, short* __restrict__ out)
{
  const int tid = threadIdx.x, w = tid >> 6, l = tid & 63;
  const size_t t = (size_t)blockIdx.x * 4 + w;
  float x[8]; float sum = 0.0f, ss = 0.0f;
  const bool act = l < 48;
  if (act) {
    if constexpr (sizeof(T) == 2) {
      s16x8 v = *(const s16x8*)((const short*)in + t * 384 + l * 8);
#pragma unroll
      for (int i = 0; i < 8; ++i) x[i] = bf2f(v[i]);
    } else {
      fx8 v = *(const fx8*)((const float*)in + t * 384 + l * 8);
#pragma unroll
      for (int i = 0; i < 8; ++i) x[i] = v[i];
    }
#pragma unroll
    for (int i = 0; i < 8; ++i) { sum += x[i]; ss += x[i] * x[i]; }
  }
#pragma unroll
  for (int d = 1; d < 64; d <<= 1) { sum += __shfl_xor(sum, d); ss += __shfl_xor(ss, d); }
  const float mu = sum * (1.0f / 384.0f);
  const float rs = rsqrtf(ss * (1.0f / 384.0f) - mu * mu + 1e-5f);
  if (act) {
    fx8 gv = *(const fx8*)(g + l * 8);
    fx8 bv = *(const fx8*)(bta + l * 8);
    s16x8 o;
#pragma unroll
    for (int i = 0; i < 8; ++i) o[i] = f2bf((x[i] - mu) * rs * gv[i] + bv[i]);
    *(s16x8*)(out + t * 384 + l * 8) = o;
  }
}

// xd_{k,q}[t] = 0.5*|k or q|^2 ; KQ layout [t][768] (k then q)
__global__ __launch_bounds__(256)
void xd_kernel(const short* __restrict__ kq, float* __restrict__ xdk, float* __restrict__ xdq)
{
  const int tid = threadIdx.x, w = tid >> 6, l = tid & 63;
  const size_t t = (size_t)blockIdx.x * 2 + (w >> 1);
  const int half = w & 1;
  const short* row = kq + t * 768 + half * 384;
  float ss = 0.0f;
  if (l < 48) {
    s16x8 v = *(const s16x8*)(row + l * 8);
#pragma unroll
    for (int i = 0; i < 8; ++i) { float f = bf2f(v[i]); ss += f * f; }
  }
#pragma unroll
  for (int d = 1; d < 64; d <<= 1) ss += __shfl_xor(ss, d);
  if (l == 0) { (half ? xdq : xdk)[t] = 0.5f * ss; }
}

// kp_sum[b*192+m] = sum_t kpT[b][m][t]
__global__ __launch_bounds__(256)
void rowsum_kernel(const short* __restrict__ kpT, float* __restrict__ sum)
{
  const int tid = threadIdx.x;
  const short* row = kpT + (size_t)blockIdx.x * 8192;
  float s = 0.0f;
  for (int i = tid; i < 1024; i += 256) {
    s16x8 v = ((const s16x8*)row)[i];
#pragma unroll
    for (int k = 0; k < 8; ++k) s += bf2f(v[k]);
  }
#pragma unroll
  for (int d = 1; d < 64; d <<= 1) s += __shfl_xor(s, d);
  __shared__ float ps[4];
  if ((tid & 63) == 0) ps[tid >> 6] = s;
  __syncthreads();
  if (tid == 0) sum[blockIdx.x] = ps[0] + ps[1] + ps[2] + ps[3];
}

// D[t] = qp[t,:] . kp_sum[b,:]
__global__ __launch_bounds__(256)
void d_kernel(const short* __restrict__ qp, const float* __restrict__ kpsum,
              float* __restrict__ D)
{
  const int t = blockIdx.x * 256 + threadIdx.x;
  const int b = t >> 13;
  const short* row = qp + (size_t)t * 192;
  const float* ks = kpsum + b * 192;
  float acc = 0.0f;
#pragma unroll
  for (int j = 0; j < 24; ++j) {
    s16x8 v = ((const s16x8*)row)[j];
#pragma unroll
    for (int i = 0; i < 8; ++i) acc += bf2f(v[i]) * ks[j * 8 + i];
  }
  D[t] = acc;
}

// dst[c][r] = f2bf(src[r][c]); fp32 -> bf16.
__global__ void transpose_kernel(const float* __restrict__ src, short* __restrict__ dst,
                                 int R, int Cc)
{
  __shared__ float tile[32][33];
  const int c0 = blockIdx.x * 32, r0 = blockIdx.y * 32;
  for (int i = threadIdx.y; i < 32; i += 8)
    tile[i][threadIdx.x] = src[(size_t)(r0 + i) * Cc + c0 + threadIdx.x];
  __syncthreads();
  for (int i = threadIdx.y; i < 32; i += 8)
    dst[(size_t)(c0 + i) * R + r0 + threadIdx.x] = f2bf(tile[threadIdx.x][i]);
}

__global__ void convert_kernel(const float* __restrict__ src, short* __restrict__ dst)
{
  const int i = blockIdx.x * 1024 + threadIdx.x * 4;
  fx4 v = *(const fx4*)(src + i);
  s16x4 o;
#pragma unroll
  for (int k = 0; k < 4; ++k) o[k] = f2bf(v[k]);
  *(s16x4*)(dst + i) = o;
}

// ---------------------------------------------------------------------------
// MEGA2: per 64-token block: h2 = LN2(y) -> g = gelu(h2@W1+b1)
//        -> out = y + g@W2 + b2  (fp32).  y read from global (simple rows).
// 512 threads = 8 waves: wr = w&1 (32-row group), wc = w>>1 (96-col group).
// ---------------------------------------------------------------------------
__global__ __launch_bounds__(512)
void mega2_kernel(const short* __restrict__ Y,
                  const short* __restrict__ W1, const short* __restrict__ W2,
                  const float* __restrict__ B1, const float* __restrict__ B2,
                  const float* __restrict__ LG, const float* __restrict__ LB,
                  float* __restrict__ out)
{
  __shared__ __align__(16) short Bl[384][72];
  __shared__ __align__(16) short Ybuf[64][392];
  __shared__ __align__(16) short Abuf[64][392];

  const int tid = threadIdx.x;
  const int w = tid >> 6, l = tid & 63;
  const int wr = w & 1, wc = w >> 1;
  const int lr = l & 15, lk = l >> 4;
  const int t0 = blockIdx.x * 64;

  fx4 acc[2][6];
  s16x8 breg[6];

  auto zacc = [&]() {
#pragma unroll
    for (int m = 0; m < 2; ++m)
#pragma unroll
      for (int n = 0; n < 6; ++n)
#pragma unroll
        for (int j = 0; j < 4; ++j) acc[m][n][j] = 0.0f;
  };
  auto loadB6 = [&](const short* W, int kt) {
#pragma unroll
    for (int p = 0; p < 6; ++p) {
      int lin = p * 512 + tid;
      breg[p] = *(const s16x8*)(W + (size_t)(lin >> 3) * 384 + kt * 64 + (lin & 7) * 8);
    }
  };
  auto storeB6 = [&]() {
#pragma unroll
    for (int p = 0; p < 6; ++p) {
      int lin = p * 512 + tid;
      *(s16x8*)&Bl[lin >> 3][(lin & 7) * 8] = breg[p];
    }
  };

  // ---- load y rows into Ybuf: 64 x 384 = 512 thr x 6 x 8 shorts ----
#pragma unroll
  for (int p = 0; p < 6; ++p) {
    int lin = p * 512 + tid;              // [0, 3072) = 64 rows x 48 chunks
    int r = lin / 48, c = (lin % 48) * 8;
    *(s16x8*)&Ybuf[r][c] = *(const s16x8*)(Y + (size_t)(t0 + r) * 384 + c);
  }
  __syncthreads();

  // ---- LN2: Ybuf -> Abuf ----
  {
    const int r = tid >> 3, seg = tid & 7;
    float xv[48]; float sum = 0.0f, ss = 0.0f;
#pragma unroll
    for (int j2 = 0; j2 < 6; ++j2) {
      s16x8 vv = *(const s16x8*)&Ybuf[r][seg * 48 + j2 * 8];
#pragma unroll
      for (int i = 0; i < 8; ++i) { float f = bf2f(vv[i]); xv[j2 * 8 + i] = f; sum += f; ss += f * f; }
    }
    sum += __shfl_xor(sum, 1); sum += __shfl_xor(sum, 2); sum += __shfl_xor(sum, 4);
    ss  += __shfl_xor(ss, 1);  ss  += __shfl_xor(ss, 2);  ss  += __shfl_xor(ss, 4);
    const float mu = sum * (1.0f / 384.0f);
    const float rs = rsqrtf(ss * (1.0f / 384.0f) - mu * mu + 1e-5f);
#pragma unroll
    for (int j2 = 0; j2 < 6; ++j2) {
      fx4 g0 = *(const fx4*)(LG + seg * 48 + j2 * 8);
      fx4 g1 = *(const fx4*)(LG + seg * 48 + j2 * 8 + 4);
      fx4 b0 = *(const fx4*)(LB + seg * 48 + j2 * 8);
      fx4 b1v = *(const fx4*)(LB + seg * 48 + j2 * 8 + 4);
      s16x8 o;
#pragma unroll
      for (int i = 0; i < 4; ++i) o[i] = f2bf((xv[j2 * 8 + i] - mu) * rs * g0[i] + b0[i]);
#pragma unroll
      for (int i = 0; i < 4; ++i) o[4 + i] = f2bf((xv[j2 * 8 + 4 + i] - mu) * rs * g1[i] + b1v[i]);
      *(s16x8*)&Abuf[r][seg * 48 + j2 * 8] = o;
    }
  }
  __syncthreads();   // h2 complete

  // ---- GEMM mlp1 (K=384) + b1 + GELU -> Abuf ----
  zacc();
  loadB6(W1, 0);
  for (int kt = 0; kt < 6; ++kt) {
    __syncthreads();
    storeB6();
    if (kt < 5) loadB6(W1, kt + 1);
    __syncthreads();
#pragma unroll
    for (int k2 = 0; k2 < 2; ++k2) {
      s16x8 af0 = *(const s16x8*)&Abuf[wr * 32 + lr][kt * 64 + k2 * 32 + lk * 8];
      s16x8 af1 = *(const s16x8*)&Abuf[wr * 32 + 16 + lr][kt * 64 + k2 * 32 + lk * 8];
#pragma unroll
      for (int n = 0; n < 6; ++n) {
        s16x8 bfr = *(const s16x8*)&Bl[wc * 96 + n * 16 + lr][k2 * 32 + lk * 8];
        mfma_bf16(acc[0][n], af0, bfr);
        mfma_bf16(acc[1][n], af1, bfr);
      }
    }
  }
  __syncthreads();   // all h2 reads done before overwrite
#pragma unroll
  for (int m = 0; m < 2; ++m)
#pragma unroll
    for (int n = 0; n < 6; ++n) {
      const int ccol = wc * 96 + n * 16 + lr;
      const float bb = B1[ccol];
#pragma unroll
      for (int j = 0; j < 4; ++j) {
        const int crow = wr * 32 + m * 16 + lk * 4 + j;
        float v = acc[m][n][j] + bb;
        v = 0.5f * v * (1.0f + erff(v * 0.70710678118654752f));
        Abuf[crow][ccol] = f2bf(v);
      }
    }

  // ---- GEMM mlp2 (K=384) + b2 + y residual -> out (fp32) ----
  zacc();
  loadB6(W2, 0);
  for (int kt = 0; kt < 6; ++kt) {
    __syncthreads();               // kt=0: gelu Abuf writes visible
    storeB6();
    if (kt < 5) loadB6(W2, kt + 1);
    __syncthreads();
#pragma unroll
    for (int k2 = 0; k2 < 2; ++k2) {
      s16x8 af0 = *(const s16x8*)&Abuf[wr * 32 + lr][kt * 64 + k2 * 32 + lk * 8];
      s16x8 af1 = *(const s16x8*)&Abuf[wr * 32 + 16 + lr][kt * 64 + k2 * 32 + lk * 8];
#pragma unroll
      for (int n = 0; n < 6; ++n) {
        s16x8 bfr = *(const s16x8*)&Bl[wc * 96 + n * 16 + lr][k2 * 32 + lk * 8];
        mfma_bf16(acc[0][n], af0, bfr);
        mfma_bf16(acc[1][n], af1, bfr);
      }
    }
  }
#pragma unroll
  for (int m = 0; m < 2; ++m)
#pragma unroll
    for (int n = 0; n < 6; ++n) {
      const int ccol = wc * 96 + n * 16 + lr;
      const float bb = B2[ccol];
#pragma unroll
      for (int j = 0; j < 4; ++j) {
        const int crow = wr * 32 + m * 16 + lk * 4 + j;
        out[(size_t)(t0 + crow) * 384 + ccol] = acc[m][n][j] + bb + bf2f(Ybuf[crow][ccol]);
      }
    }
}

extern "C" void kernel_launch(void* const* d_in, const int* in_sizes, int n_in,
                              void* d_out, int out_size, void* d_ws, size_t ws_size,
                              hipStream_t stream)
{
  const float* x      = (const float*)d_in[0];
  const float* w      = (const float*)d_in[1];   // [192][384], already k-contig
  const float* kqv_w  = (const float*)d_in[2];   // [384][1152]
  const float* kqv_b  = (const float*)d_in[3];
  const float* proj_w = (const float*)d_in[4];
  const float* proj_b = (const float*)d_in[5];
  const float* ln1_g  = (const float*)d_in[6];
  const float* ln1_b  = (const float*)d_in[7];
  const float* ln2_g  = (const float*)d_in[8];
  const float* ln2_b  = (const float*)d_in[9];
  const float* w1     = (const float*)d_in[10];
  const float* b1     = (const float*)d_in[11];
  const float* w2     = (const float*)d_in[12];
  const float* b2     = (const float*)d_in[13];

  char* p = (char*)d_ws;
  auto take = [&](size_t n) { char* r = p; p += (n + 255) & ~(size_t)255; return r; };
  short* wtKQV  = (short*)take(1152 * 384 * 2);
  short* wtPROJ = (short*)take(384 * 384 * 2);
  short* wtM1   = (short*)take(384 * 384 * 2);
  short* wtM2   = (short*)take(384 * 384 * 2);
  short* wB     = (short*)take(192 * 384 * 2);
  short* KQ     = (short*)take((size_t)65536 * 768 * 2);   // 100.7 MB; later YA, KPART
  short* VT     = (short*)take((size_t)8 * 384 * 8192 * 2); // 50.3 MB
  char*  KPQ    = take(50331648);                           // H -> (KPT|QP) -> Y
  float* XDK   = (float*)take(262144);
  float* XDQ   = (float*)take(262144);
  float* DV    = (float*)take(262144);
  float* KPSUM = (float*)take(1536 * 4);
  float* KPART = (float*)take((size_t)64 * 73728 * 4);      // 18.9 MB
  short* KPTVB = (short*)take(1179648);

  short* H   = (short*)KPQ;
  short* KPT = (short*)KPQ;
  short* QP  = (short*)(KPQ + 25165824);
  short* Y   = (short*)KPQ;    // overwrites KPT/QP (both dead before proj writes)
  short* YA  = KQ;             // KQ dead after qp gemm

  const float ESC = 0.07216878364870323f;  // 1/sqrt(192)
  dim3 blk(256);

  transpose_kernel<<<dim3(36, 12), dim3(32, 8), 0, stream>>>(kqv_w, wtKQV, 384, 1152);
  transpose_kernel<<<dim3(12, 12), dim3(32, 8), 0, stream>>>(proj_w, wtPROJ, 384, 384);
  transpose_kernel<<<dim3(12, 12), dim3(32, 8), 0, stream>>>(w1, wtM1, 384, 384);
  transpose_kernel<<<dim3(12, 12), dim3(32, 8), 0, stream>>>(w2, wtM2, 384, 384);
  convert_kernel<<<72, blk, 0, stream>>>(w, wB);

  // h = LN1(x)
  ln_kernel<float><<<16384, blk, 0, stream>>>(x, ln1_g, ln1_b, H);

  // kq + vT scatter = h @ kqv_w + b
  gemm_tn<128, 128, M_BIAS | M_KQVT><<<dim3(9, 512), blk, 0, stream>>>(
      H, 384, wtKQV, 384, 0, KQ, 768, 384, kqv_b, nullptr, 0.f, nullptr, 0, 0, VT);

  xd_kernel<<<32768, blk, 0, stream>>>(KQ, XDK, XDQ);

  // kp^T[b][m][t] = exp(k@w^T - xd_k)/sqrt(m)
  gemm_tn<128, 64, M_EXP | M_TSTORE><<<dim3(3, 512), blk, 0, stream>>>(
      KQ, 768, wB, 384, 0, KPT, 192, 384, nullptr, XDK, ESC, nullptr, 0, 0, nullptr);
  // qp[t][m] = exp(q@w^T - xd_q)/sqrt(m)
  gemm_tn<128, 64, M_EXP><<<dim3(3, 512), blk, 0, stream>>>(
      KQ + 384, 768, wB, 384, 0, QP, 192, 384, nullptr, XDQ, ESC, nullptr, 0, 0, nullptr);

  rowsum_kernel<<<1536, blk, 0, stream>>>(KPT, KPSUM);
  d_kernel<<<256, blk, 0, stream>>>(QP, KPSUM, DV);

  // kptv[b][n][m] via deterministic split-K partials
  gemm_kptv<<<dim3(3, 3, 64), blk, 0, stream>>>(VT, KPT, KPART);
  kptv_reduce<<<2304, blk, 0, stream>>>(KPART, KPTVB);

  // ya = (qp @ kptv^T) / (D + eps)
  gemm_tn<128, 128, M_DIV | M_BATCHBT><<<dim3(3, 512), blk, 0, stream>>>(
      QP, 192, KPTVB, 192, 73728, YA, 384, 192, nullptr, DV, 0.f, nullptr, 0, 0, nullptr);

  // y = v + ya @ proj_w + proj_b   (v residual read transposed from VT)
  gemm_tn<128, 128, M_BIAS | M_RESIDT><<<dim3(3, 512), blk, 0, stream>>>(
      YA, 384, wtPROJ, 384, 0, Y, 384, 384, proj_b, nullptr, 0.f, VT, 384, 0, nullptr);

  // h2=LN2(y) -> g=gelu(h2@W1+b1) -> out = y + g@W2 + b2, fused
  mega2_kernel<<<1024, dim3(512), 0, stream>>>(
      Y, wtM1, wtM2, b1, b2, ln2_g, ln2_b, (float*)d_out);
}

// Round 11
// 486.431 us; speedup vs baseline: 1.0651x; 1.0651x over previous
//
#include <hip/hip_runtime.h>
#include <cstdint>
#include <cstddef>

// ---------------------------------------------------------------------------
// Performer block. fp32 in/out, bf16 MFMA internally.
// R11 = R7 pipeline (tail reverted from R10's slower mega2) + fused in-GEMM
// reductions: M_XA computes xd_k/xd_q inside kp/qp staging (blocks stage the
// full K=384 row anyway); M_DOTB computes D inside ya staging (K=192 rows).
// Deletes xd_kernel + d_kernel + XDK/XDQ/DV round-trips.
// ws peak ~224 MB.
// ---------------------------------------------------------------------------

typedef __attribute__((ext_vector_type(8))) short s16x8;
typedef __attribute__((ext_vector_type(4))) short s16x4;
typedef __attribute__((ext_vector_type(4))) float fx4;
typedef __attribute__((ext_vector_type(8))) float fx8;

__device__ __forceinline__ float bf2f(short s) {
  union { float f; unsigned u; } z; z.u = ((unsigned)(unsigned short)s) << 16; return z.f;
}
__device__ __forceinline__ short f2bf(float f) {
  union { float f; unsigned u; } z; z.f = f;
  unsigned u = z.u;
  u += 0x7fffu + ((u >> 16) & 1u);   // RNE
  return (short)(u >> 16);
}

__device__ __forceinline__ void mfma_bf16(fx4& d, s16x8 a, s16x8 b) {
  asm("v_mfma_f32_16x16x32_bf16 %0, %1, %2, %0" : "+v"(d) : "v"(a), "v"(b));
}

enum : int { M_BIAS=1, M_EXP=2, M_DIV=4, M_RESID=8, M_GELU=16, M_TSTORE=32,
             M_BATCHBT=64, M_KQVT=128, M_RESIDT=256, M_F32OUT=512,
             M_XA=1024, M_DOTB=2048 };

// C[row][col] = sum_k A[row][k] * Bt[col][k]  (both operands k-contiguous bf16)
// Col-fast grid + bijective XCD chunk swizzle (nwg % 8 == 0).
// LDS: single 32KB buffer, 2-barrier loop, reg-staged prefetch, XOR swizzle.
// M_XA:  xdl[row] = 0.5 * sum_k A[row][k]^2     (requires block stages full K)
// M_DOTB: xdl[row] = sum_k A[row][k]*rowvec[b*192+k]  (D for the ya GEMM)
template<int BM, int BN, int MODE>
__global__ __launch_bounds__(256)
void gemm_tn(const short* __restrict__ A, int lda,
             const short* __restrict__ Bt, int ldbt, long btStride,
             short* __restrict__ C, int ldc,
             int K,
             const float* __restrict__ bias,
             const float* __restrict__ rowvec, float escale,
             const short* __restrict__ resid, int ldr, int rcol,
             short* __restrict__ vt)
{
  constexpr int WM = BM / 2, WN = BN / 2, MR = WM / 16, NR = WN / 16;
  constexpr int AIT = BM * 8 / 256, BIT = BN * 8 / 256;
  __shared__ __align__(16) short Al[BM][64];
  __shared__ __align__(16) short Bl[BN][64];
  __shared__ float xdl[(MODE & (M_XA | M_DOTB)) ? BM : 1];

  const int tid = threadIdx.x;
  const int gx = gridDim.x;
  const int nwg = gx * gridDim.y;
  const int o = blockIdx.x + gx * blockIdx.y;        // hw dispatch order id
  const int swz = (o & 7) * (nwg >> 3) + (o >> 3);   // bijective for nwg%8==0
  const int bx = swz % gx, by = swz / gx;            // col fast within chunk
  const int row0 = by * BM, col0 = bx * BN;

  const short* Bt2 = (MODE & M_BATCHBT)
      ? Bt + (size_t)(row0 >> 13) * (size_t)btStride : Bt;
  const int w = tid >> 6, l = tid & 63;
  const int wr = w >> 1, wc = w & 1;
  const int lr = l & 15, lk = l >> 4;

  fx4 acc[MR][NR];
#pragma unroll
  for (int m = 0; m < MR; ++m)
#pragma unroll
    for (int n = 0; n < NR; ++n)
#pragma unroll
      for (int j = 0; j < 4; ++j) acc[m][n][j] = 0.0f;

  s16x8 areg[AIT], breg[BIT];
  float xacc[(MODE & (M_XA | M_DOTB)) ? AIT : 1];
#pragma unroll
  for (int i = 0; i < (int)(sizeof(xacc) / sizeof(float)); ++i) xacc[i] = 0.0f;

  auto loadA = [&](int kt) {
    const short* p = A + (size_t)row0 * lda + kt * 64;
#pragma unroll
    for (int i = 0; i < AIT; ++i) {
      int ch = i * 256 + tid;
      areg[i] = *(const s16x8*)(p + (size_t)(ch >> 3) * lda + ((ch & 7) * 8));
      if (MODE & M_XA) {
#pragma unroll
        for (int jj = 0; jj < 8; ++jj) { float f = bf2f(areg[i][jj]); xacc[i] += f * f; }
      }
      if (MODE & M_DOTB) {
        const float* dv = rowvec + (row0 >> 13) * 192 + kt * 64 + (ch & 7) * 8;
#pragma unroll
        for (int jj = 0; jj < 8; ++jj) xacc[i] += bf2f(areg[i][jj]) * dv[jj];
      }
    }
  };
  auto loadB = [&](int kt) {
    const short* p = Bt2 + (size_t)col0 * ldbt + kt * 64;
#pragma unroll
    for (int i = 0; i < BIT; ++i) {
      int ch = i * 256 + tid;
      breg[i] = *(const s16x8*)(p + (size_t)(ch >> 3) * ldbt + ((ch & 7) * 8));
    }
  };
  // swizzled LDS store: chunk (ch&7) ^ (row&7)
  auto storeA = [&]() {
#pragma unroll
    for (int i = 0; i < AIT; ++i) {
      int ch = i * 256 + tid, row = ch >> 3;
      *(s16x8*)&Al[row][((ch ^ row) & 7) * 8] = areg[i];
    }
  };
  auto storeB = [&]() {
#pragma unroll
    for (int i = 0; i < BIT; ++i) {
      int ch = i * 256 + tid, row = ch >> 3;
      *(s16x8*)&Bl[row][((ch ^ row) & 7) * 8] = breg[i];
    }
  };

  const int NT = K / 64;
  loadA(0); loadB(0); storeA(); storeB();
  __syncthreads();
  for (int kt = 0; kt < NT; ++kt) {
    if (kt + 1 < NT) { loadA(kt + 1); loadB(kt + 1); }
#pragma unroll
    for (int kk = 0; kk < 2; ++kk) {
      s16x8 af[MR], bfr[NR];
#pragma unroll
      for (int m = 0; m < MR; ++m) {
        const int ar = wr * WM + m * 16 + lr;
        af[m] = *(const s16x8*)&Al[ar][(((kk * 4 + lk) ^ ar) & 7) * 8];
      }
#pragma unroll
      for (int n = 0; n < NR; ++n) {
        const int br = wc * WN + n * 16 + lr;
        bfr[n] = *(const s16x8*)&Bl[br][(((kk * 4 + lk) ^ br) & 7) * 8];
      }
#pragma unroll
      for (int m = 0; m < MR; ++m)
#pragma unroll
        for (int n = 0; n < NR; ++n)
          mfma_bf16(acc[m][n], af[m], bfr[n]);
    }
    if (kt + 1 < NT) {
      __syncthreads();            // all reads of the buffer done
      storeA(); storeB();         // overwrite with next tile
      __syncthreads();            // stores visible
    }
  }

  // fused per-row reduction: 8 threads (consecutive tids) cover row r's chunks
  if (MODE & (M_XA | M_DOTB)) {
#pragma unroll
    for (int i = 0; i < (int)(sizeof(xacc) / sizeof(float)); ++i) {
      float s = xacc[i];
      s += __shfl_xor(s, 1); s += __shfl_xor(s, 2); s += __shfl_xor(s, 4);
      if ((tid & 7) == 0) xdl[i * 32 + (tid >> 3)] = (MODE & M_XA) ? 0.5f * s : s;
    }
    __syncthreads();
  }

  // C/D layout (m89): col = lane&15, row = (lane>>4)*4 + j.
#pragma unroll
  for (int m = 0; m < MR; ++m) {
#pragma unroll
    for (int n = 0; n < NR; ++n) {
      const int gcol = col0 + wc * WN + n * 16 + lr;
      const float bv = (MODE & M_BIAS) ? bias[gcol] : 0.0f;
#pragma unroll
      for (int j = 0; j < 4; ++j) {
        const int lrow = wr * WM + m * 16 + lk * 4 + j;
        const int grow = row0 + lrow;
        float v = acc[m][n][j] + bv;
        if (MODE & M_EXP)  v = expf(v - xdl[lrow]) * escale;
        if (MODE & M_DIV)  v = v / (xdl[lrow] + 1e-8f);
        if (MODE & M_GELU) v = 0.5f * v * (1.0f + erff(v * 0.70710678118654752f));
        if (MODE & M_RESID)  v += bf2f(resid[(size_t)grow * ldr + rcol + gcol]);
        if (MODE & M_RESIDT) v += bf2f(resid[((size_t)((grow >> 13) * ldr + gcol)) * 8192 + (grow & 8191)]);
        if (MODE & M_F32OUT) {
          ((float*)C)[(size_t)grow * ldc + gcol] = v;
        } else if (MODE & M_TSTORE) {
          C[((size_t)((grow >> 13) * ldc + gcol)) * 8192 + (grow & 8191)] = f2bf(v);
        } else if (MODE & M_KQVT) {
          if (gcol < 768) C[(size_t)grow * 768 + gcol] = f2bf(v);
          else vt[((size_t)((grow >> 13) * 384 + (gcol - 768))) * 8192 + (grow & 8191)] = f2bf(v);
        } else {
          C[(size_t)grow * ldc + gcol] = f2bf(v);
        }
      }
    }
  }
}

// kptv partials: part[z=b*8+s][n][m] = sum_{t in split s} v[t,n]*kp[t,m]
__global__ __launch_bounds__(256)
void gemm_kptv(const short* __restrict__ vT, const short* __restrict__ kpT,
               float* __restrict__ part)
{
  __shared__ __align__(16) short Al[128][64];
  __shared__ __align__(16) short Bl[64][64];
  const int tid = threadIdx.x;
  const int b = blockIdx.z >> 3, s = blockIdx.z & 7;
  const int row0 = blockIdx.x * 128, col0 = blockIdx.y * 64;
  const short* A  = vT  + ((size_t)(b * 384 + row0)) * 8192 + s * 1024;
  const short* Bt = kpT + ((size_t)(b * 192 + col0)) * 8192 + s * 1024;
  const int w = tid >> 6, l = tid & 63;
  const int wr = w >> 1, wc = w & 1, lr = l & 15, lk = l >> 4;

  fx4 acc[4][2];
#pragma unroll
  for (int m = 0; m < 4; ++m)
#pragma unroll
    for (int n = 0; n < 2; ++n)
#pragma unroll
      for (int j = 0; j < 4; ++j) acc[m][n][j] = 0.0f;

  s16x8 areg[4], breg[2];
  auto loadA = [&](int kt) {
#pragma unroll
    for (int i = 0; i < 4; ++i) {
      int ch = i * 256 + tid;
      areg[i] = *(const s16x8*)(A + kt * 64 + (size_t)(ch >> 3) * 8192 + ((ch & 7) * 8));
    }
  };
  auto loadB = [&](int kt) {
#pragma unroll
    for (int i = 0; i < 2; ++i) {
      int ch = i * 256 + tid;
      breg[i] = *(const s16x8*)(Bt + kt * 64 + (size_t)(ch >> 3) * 8192 + ((ch & 7) * 8));
    }
  };
  auto storeA = [&]() {
#pragma unroll
    for (int i = 0; i < 4; ++i) {
      int ch = i * 256 + tid, row = ch >> 3;
      *(s16x8*)&Al[row][((ch ^ row) & 7) * 8] = areg[i];
    }
  };
  auto storeB = [&]() {
#pragma unroll
    for (int i = 0; i < 2; ++i) {
      int ch = i * 256 + tid, row = ch >> 3;
      *(s16x8*)&Bl[row][((ch ^ row) & 7) * 8] = breg[i];
    }
  };

  loadA(0); loadB(0); storeA(); storeB();
  __syncthreads();
  for (int kt = 0; kt < 16; ++kt) {
    if (kt + 1 < 16) { loadA(kt + 1); loadB(kt + 1); }
#pragma unroll
    for (int kk = 0; kk < 2; ++kk) {
      s16x8 af[4], bfr[2];
#pragma unroll
      for (int m = 0; m < 4; ++m) {
        const int ar = wr * 64 + m * 16 + lr;
        af[m] = *(const s16x8*)&Al[ar][(((kk * 4 + lk) ^ ar) & 7) * 8];
      }
#pragma unroll
      for (int n = 0; n < 2; ++n) {
        const int br = wc * 32 + n * 16 + lr;
        bfr[n] = *(const s16x8*)&Bl[br][(((kk * 4 + lk) ^ br) & 7) * 8];
      }
#pragma unroll
      for (int m = 0; m < 4; ++m)
#pragma unroll
        for (int n = 0; n < 2; ++n)
          mfma_bf16(acc[m][n], af[m], bfr[n]);
    }
    if (kt + 1 < 16) {
      __syncthreads();
      storeA(); storeB();
      __syncthreads();
    }
  }

  float* outp = part + (size_t)blockIdx.z * 73728;
#pragma unroll
  for (int m = 0; m < 4; ++m)
#pragma unroll
    for (int n = 0; n < 2; ++n) {
      const int gm = col0 + wc * 32 + n * 16 + lr;
#pragma unroll
      for (int j = 0; j < 4; ++j) {
        const int gn = row0 + wr * 64 + m * 16 + lk * 4 + j;
        outp[(size_t)gn * 192 + gm] = acc[m][n][j];
      }
    }
}

__global__ void kptv_reduce(const float* __restrict__ part, short* __restrict__ outb)
{
  const int i = blockIdx.x * 256 + threadIdx.x;   // i = b*73728 + n*192 + m
  const int b = i / 73728, j = i - b * 73728;
  const float* p = part + (size_t)b * 8 * 73728 + j;
  float s = 0.0f;
#pragma unroll
  for (int k = 0; k < 8; ++k) s += p[(size_t)k * 73728];
  outb[i] = f2bf(s);
}

// LayerNorm over 384, one wave per token.
template<typename T>
__global__ __launch_bounds__(256)
void ln_kernel(const T* __restrict__ in, const float* __restrict__ g,
               const float* __restrict__ bta, short* __restrict__ out)
{
  const int tid = threadIdx.x, w = tid >> 6, l = tid & 63;
  const size_t t = (size_t)blockIdx.x * 4 + w;
  float x[8]; float sum = 0.0f, ss = 0.0f;
  const bool act = l < 48;
  if (act) {
    if constexpr (sizeof(T) == 2) {
      s16x8 v = *(const s16x8*)((const short*)in + t * 384 + l * 8);
#pragma unroll
      for (int i = 0; i < 8; ++i) x[i] = bf2f(v[i]);
    } else {
      fx8 v = *(const fx8*)((const float*)in + t * 384 + l * 8);
#pragma unroll
      for (int i = 0; i < 8; ++i) x[i] = v[i];
    }
#pragma unroll
    for (int i = 0; i < 8; ++i) { sum += x[i]; ss += x[i] * x[i]; }
  }
#pragma unroll
  for (int d = 1; d < 64; d <<= 1) { sum += __shfl_xor(sum, d); ss += __shfl_xor(ss, d); }
  const float mu = sum * (1.0f / 384.0f);
  const float rs = rsqrtf(ss * (1.0f / 384.0f) - mu * mu + 1e-5f);
  if (act) {
    fx8 gv = *(const fx8*)(g + l * 8);
    fx8 bv = *(const fx8*)(bta + l * 8);
    s16x8 o;
#pragma unroll
    for (int i = 0; i < 8; ++i) o[i] = f2bf((x[i] - mu) * rs * gv[i] + bv[i]);
    *(s16x8*)(out + t * 384 + l * 8) = o;
  }
}

// kp_sum[b*192+m] = sum_t kpT[b][m][t]
__global__ __launch_bounds__(256)
void rowsum_kernel(const short* __restrict__ kpT, float* __restrict__ sum)
{
  const int tid = threadIdx.x;
  const short* row = kpT + (size_t)blockIdx.x * 8192;
  float s = 0.0f;
  for (int i = tid; i < 1024; i += 256) {
    s16x8 v = ((const s16x8*)row)[i];
#pragma unroll
    for (int k = 0; k < 8; ++k) s += bf2f(v[k]);
  }
#pragma unroll
  for (int d = 1; d < 64; d <<= 1) s += __shfl_xor(s, d);
  __shared__ float ps[4];
  if ((tid & 63) == 0) ps[tid >> 6] = s;
  __syncthreads();
  if (tid == 0) sum[blockIdx.x] = ps[0] + ps[1] + ps[2] + ps[3];
}

// dst[c][r] = f2bf(src[r][c]); fp32 -> bf16.
__global__ void transpose_kernel(const float* __restrict__ src, short* __restrict__ dst,
                                 int R, int Cc)
{
  __shared__ float tile[32][33];
  const int c0 = blockIdx.x * 32, r0 = blockIdx.y * 32;
  for (int i = threadIdx.y; i < 32; i += 8)
    tile[i][threadIdx.x] = src[(size_t)(r0 + i) * Cc + c0 + threadIdx.x];
  __syncthreads();
  for (int i = threadIdx.y; i < 32; i += 8)
    dst[(size_t)(c0 + i) * R + r0 + threadIdx.x] = f2bf(tile[threadIdx.x][i]);
}

__global__ void convert_kernel(const float* __restrict__ src, short* __restrict__ dst)
{
  const int i = blockIdx.x * 1024 + threadIdx.x * 4;
  fx4 v = *(const fx4*)(src + i);
  s16x4 o;
#pragma unroll
  for (int k = 0; k < 4; ++k) o[k] = f2bf(v[k]);
  *(s16x4*)(dst + i) = o;
}

extern "C" void kernel_launch(void* const* d_in, const int* in_sizes, int n_in,
                              void* d_out, int out_size, void* d_ws, size_t ws_size,
                              hipStream_t stream)
{
  const float* x      = (const float*)d_in[0];
  const float* w      = (const float*)d_in[1];   // [192][384], already k-contig
  const float* kqv_w  = (const float*)d_in[2];   // [384][1152]
  const float* kqv_b  = (const float*)d_in[3];
  const float* proj_w = (const float*)d_in[4];
  const float* proj_b = (const float*)d_in[5];
  const float* ln1_g  = (const float*)d_in[6];
  const float* ln1_b  = (const float*)d_in[7];
  const float* ln2_g  = (const float*)d_in[8];
  const float* ln2_b  = (const float*)d_in[9];
  const float* w1     = (const float*)d_in[10];
  const float* b1     = (const float*)d_in[11];
  const float* w2     = (const float*)d_in[12];
  const float* b2     = (const float*)d_in[13];

  char* p = (char*)d_ws;
  auto take = [&](size_t n) { char* r = p; p += (n + 255) & ~(size_t)255; return r; };
  short* wtKQV  = (short*)take(1152 * 384 * 2);
  short* wtPROJ = (short*)take(384 * 384 * 2);
  short* wtM1   = (short*)take(384 * 384 * 2);
  short* wtM2   = (short*)take(384 * 384 * 2);
  short* wB     = (short*)take(192 * 384 * 2);
  short* KQ     = (short*)take((size_t)65536 * 768 * 2);   // 100.7 MB; later YA, G
  short* VT     = (short*)take((size_t)8 * 384 * 8192 * 2); // 50.3 MB; later H2
  char*  KPQ    = take(50331648);                           // H -> (KPT|QP) -> Y
  float* KPSUM = (float*)take(1536 * 4);
  float* KPART = (float*)take((size_t)64 * 73728 * 4);      // 18.9 MB
  short* KPTVB = (short*)take(1179648);

  short* H   = (short*)KPQ;
  short* KPT = (short*)KPQ;
  short* QP  = (short*)(KPQ + 25165824);
  short* Y   = (short*)KPQ;
  short* YA  = KQ;   // KQ dead after qp gemm
  short* G   = KQ;   // YA dead after proj
  short* H2  = VT;   // VT dead after proj

  const float ESC = 0.07216878364870323f;  // 1/sqrt(192)
  dim3 blk(256);

  transpose_kernel<<<dim3(36, 12), dim3(32, 8), 0, stream>>>(kqv_w, wtKQV, 384, 1152);
  transpose_kernel<<<dim3(12, 12), dim3(32, 8), 0, stream>>>(proj_w, wtPROJ, 384, 384);
  transpose_kernel<<<dim3(12, 12), dim3(32, 8), 0, stream>>>(w1, wtM1, 384, 384);
  transpose_kernel<<<dim3(12, 12), dim3(32, 8), 0, stream>>>(w2, wtM2, 384, 384);
  convert_kernel<<<72, blk, 0, stream>>>(w, wB);

  // h = LN1(x)
  ln_kernel<float><<<16384, blk, 0, stream>>>(x, ln1_g, ln1_b, H);

  // kq + vT scatter = h @ kqv_w + b
  gemm_tn<128, 128, M_BIAS | M_KQVT><<<dim3(9, 512), blk, 0, stream>>>(
      H, 384, wtKQV, 384, 0, KQ, 768, 384, kqv_b, nullptr, 0.f, nullptr, 0, 0, VT);

  // kp^T[b][m][t] = exp(k@w^T - xd_k)/sqrt(m)   (xd fused via M_XA)
  gemm_tn<128, 64, M_EXP | M_TSTORE | M_XA><<<dim3(3, 512), blk, 0, stream>>>(
      KQ, 768, wB, 384, 0, KPT, 192, 384, nullptr, nullptr, ESC, nullptr, 0, 0, nullptr);
  // qp[t][m] = exp(q@w^T - xd_q)/sqrt(m)        (xd fused via M_XA)
  gemm_tn<128, 64, M_EXP | M_XA><<<dim3(3, 512), blk, 0, stream>>>(
      KQ + 384, 768, wB, 384, 0, QP, 192, 384, nullptr, nullptr, ESC, nullptr, 0, 0, nullptr);

  rowsum_kernel<<<1536, blk, 0, stream>>>(KPT, KPSUM);

  // kptv[b][n][m] via deterministic split-K partials
  gemm_kptv<<<dim3(3, 3, 64), blk, 0, stream>>>(VT, KPT, KPART);
  kptv_reduce<<<2304, blk, 0, stream>>>(KPART, KPTVB);

  // ya = (qp @ kptv^T) / (D + eps)   (D fused via M_DOTB with kpsum)
  gemm_tn<128, 128, M_DIV | M_BATCHBT | M_DOTB><<<dim3(3, 512), blk, 0, stream>>>(
      QP, 192, KPTVB, 192, 73728, YA, 384, 192, nullptr, KPSUM, 0.f, nullptr, 0, 0, nullptr);

  // y = v + ya @ proj_w + proj_b   (v residual read transposed from VT)
  gemm_tn<128, 128, M_BIAS | M_RESIDT><<<dim3(3, 512), blk, 0, stream>>>(
      YA, 384, wtPROJ, 384, 0, Y, 384, 384, proj_b, nullptr, 0.f, VT, 384, 0, nullptr);

  // h2 = LN2(y)
  ln_kernel<short><<<16384, blk, 0, stream>>>(Y, ln2_g, ln2_b, H2);

  // g = gelu(h2 @ w1 + b1)
  gemm_tn<128, 128, M_BIAS | M_GELU><<<dim3(3, 512), blk, 0, stream>>>(
      H2, 384, wtM1, 384, 0, G, 384, 384, b1, nullptr, 0.f, nullptr, 0, 0, nullptr);

  // out = y + g @ w2 + b2   (fp32 out)
  gemm_tn<128, 128, M_BIAS | M_RESID | M_F32OUT><<<dim3(3, 512), blk, 0, stream>>>(
      G, 384, wtM2, 384, 0, (short*)d_out, 384, 384, b2, nullptr, 0.f, Y, 384, 0, nullptr);
}